// Round 7
// baseline (365.638 us; speedup 1.0000x reference)
//
#include <hip/hip_runtime.h>
#include <math.h>

typedef __bf16 bf16x8 __attribute__((ext_vector_type(8)));
typedef float f32x4 __attribute__((ext_vector_type(4)));

// ---------------- weight conversion: fp32 -> bf16, LDS-image layout -----------
// ws element map (bf16 units):
//   [0,16384)      L1 kt0/kt1 full frags: (kt*16+nt)*512 + lane*8
//   [16384,20480)  L1 kt2 half-frags (k=64..79): 16384 + nt*256 + lane*8 (lane<32)
//   [20480,53248)  L2 frags: 20480 + (kt*8+nt)*512 + lane*8
//   [53248,61440)  L3 frags: 53248 + (kt*4+nt)*512 + lane*8
//   [61440,68608)  L4 frags (nt<7): 61440 + (kt*7+nt)*512 + lane*8  (stays global)
// Frag = 32x16 (or 16x16 half) block of B; lane L holds B[kt*32+(L>>4)*8+j][nt*16+(L&15)].
__global__ void conv_weights(const float* __restrict__ W1, const float* __restrict__ W2,
                             const float* __restrict__ W3, const float* __restrict__ W4,
                             __bf16* __restrict__ ws)
{
  const int f = blockIdx.x * 4 + (threadIdx.x >> 6);
  const int lane = threadIdx.x & 63;
  if (f >= 142) return;
  const int q = lane >> 4, c = lane & 15;
  bf16x8 v;
  if (f < 32) {                       // L1 kt0/kt1
    const int kt = f >> 4, nt = f & 15;
    const int n = nt * 16 + c;
#pragma unroll
    for (int j = 0; j < 8; ++j) v[j] = (__bf16)W1[(kt * 32 + q * 8 + j) * 256 + n];
    *(bf16x8*)(ws + f * 512 + lane * 8) = v;
  } else if (f < 48) {                // L1 kt2 half (rows 64..79)
    if (lane < 32) {
      const int nt = f - 32;
      const int n = nt * 16 + c;
#pragma unroll
      for (int j = 0; j < 8; ++j) v[j] = (__bf16)W1[(64 + q * 8 + j) * 256 + n];
      *(bf16x8*)(ws + 16384 + nt * 256 + lane * 8) = v;
    }
  } else if (f < 112) {               // L2 (256x128)
    const int f0 = f - 48;
    const int kt = f0 >> 3, nt = f0 & 7;
    const int n = nt * 16 + c;
#pragma unroll
    for (int j = 0; j < 8; ++j) v[j] = (__bf16)W2[(kt * 32 + q * 8 + j) * 128 + n];
    *(bf16x8*)(ws + 20480 + f0 * 512 + lane * 8) = v;
  } else if (f < 128) {               // L3 (128x64)
    const int f0 = f - 112;
    const int kt = f0 >> 2, nt = f0 & 3;
    const int n = nt * 16 + c;
#pragma unroll
    for (int j = 0; j < 8; ++j) v[j] = (__bf16)W3[(kt * 32 + q * 8 + j) * 64 + n];
    *(bf16x8*)(ws + 53248 + f0 * 512 + lane * 8) = v;
  } else {                            // L4 (64x101, nt<7)
    const int f0 = f - 128;
    const int kt = f0 / 7, nt = f0 % 7;
    const int n = nt * 16 + c;
#pragma unroll
    for (int j = 0; j < 8; ++j)
      v[j] = (n < 101) ? (__bf16)W4[(kt * 32 + q * 8 + j) * 101 + n] : (__bf16)0.f;
    *(bf16x8*)(ws + 61440 + f0 * 512 + lane * 8) = v;
  }
}

// ---------------- persistent fused forward ------------------------------------
// Grid 256 blocks x 256 thr = 1 block/CU (LDS 157952 B). Stage W1-W3 into LDS
// ONCE; hoist W4 frags + all bias/gain/qsup vectors into registers (1 wave/SIMD
// -> ~450 spill-free VGPRs). Then 8 barrier-free tile iterations per wave.
// Per-wave act region 8768 B: h1[16][264]bf16 @0; h2[16][136] @0 (h1 dead);
// h3[16][72] @0 (h2 dead); proj[16][101]f32 @2304.

__global__ __launch_bounds__(256, 1)
void sacq_persist(const float* __restrict__ obs,  const float* __restrict__ act,
                  const float* __restrict__ rew,  const float* __restrict__ boot,
                  const float* __restrict__ disc, const float* __restrict__ qsup,
                  const float* __restrict__ b1, const float* __restrict__ g1, const float* __restrict__ be1,
                  const float* __restrict__ b2, const float* __restrict__ g2, const float* __restrict__ be2,
                  const float* __restrict__ b3, const float* __restrict__ g3, const float* __restrict__ be3,
                  const float* __restrict__ b4,
                  const __bf16* __restrict__ ws,
                  float* __restrict__ out)
{
  __shared__ __align__(16) char smem[157952];
  __bf16* wl = (__bf16*)smem;                       // 61440 bf16 of W1-W3
  const int t = threadIdx.x;
  const int wv = t >> 6, lane = t & 63;
  const int q = lane >> 4, c = lane & 15;
  char* hb = smem + 122880 + wv * 8768;
  __bf16* h1 = (__bf16*)hb;            // [16][264]
  __bf16* h2 = (__bf16*)hb;            // [16][136] (after h1 dead)
  __bf16* h3 = (__bf16*)hb;            // [16][72]  (after h2 dead)
  float*  proj = (float*)(hb + 2304);  // [16][101]

  // ---- stage W1-W3 image into LDS (coalesced uint4)
  {
    const uint4* src = (const uint4*)ws;
    uint4* dst = (uint4*)smem;
    for (int i = t; i < 7680; i += 256) dst[i] = src[i];
  }

  // ---- hoist loop-invariant params into registers (overlaps staging)
  float b1v[16], g1v[16], be1v[16];
#pragma unroll
  for (int nt = 0; nt < 16; ++nt) {
    const int col = nt * 16 + c;
    b1v[nt] = b1[col]; g1v[nt] = g1[col]; be1v[nt] = be1[col];
  }
  float b2v[8], g2v[8], be2v[8];
#pragma unroll
  for (int nt = 0; nt < 8; ++nt) {
    const int col = nt * 16 + c;
    b2v[nt] = b2[col]; g2v[nt] = g2[col]; be2v[nt] = be2[col];
  }
  float b3v[4], g3v[4], be3v[4];
#pragma unroll
  for (int nt = 0; nt < 4; ++nt) {
    const int col = nt * 16 + c;
    b3v[nt] = b3[col]; g3v[nt] = g3[col]; be3v[nt] = be3[col];
  }
  float b4v[7], qsv[7];
#pragma unroll
  for (int nt = 0; nt < 7; ++nt) {
    const int col = nt * 16 + c;
    b4v[nt] = (col < 101) ? b4[col] : 0.f;
    qsv[nt] = (col < 101) ? qsup[col] : 0.f;
  }
  bf16x8 B4[2][7];
#pragma unroll
  for (int kt = 0; kt < 2; ++kt)
#pragma unroll
    for (int nt = 0; nt < 7; ++nt)
      B4[kt][nt] = *(const bf16x8*)(ws + 61440 + (kt * 7 + nt) * 512 + lane * 8);

  __syncthreads();   // weights resident; no further barriers

  for (int it = 0; it < 8; ++it) {
    const int tile = it * 1024 + blockIdx.x * 4 + wv;
    const int row0 = tile * 16;

    // ---- A1 from global (float4, rows 240/80 B strided)
    bf16x8 A1[3];
    {
      const float4* ob4 = (const float4*)(obs + (size_t)(row0 + c) * 60);
      const float4* ac4 = (const float4*)(act + (size_t)(row0 + c) * 20);
#pragma unroll
      for (int kt = 0; kt < 3; ++kt) {
        const int k0 = kt * 32 + q * 8;
        float v[8];
        if (k0 < 56) {
          const float4 a = ob4[k0 / 4], b = ob4[k0 / 4 + 1];
          v[0]=a.x; v[1]=a.y; v[2]=a.z; v[3]=a.w; v[4]=b.x; v[5]=b.y; v[6]=b.z; v[7]=b.w;
        } else if (k0 == 56) {
          const float4 a = ob4[14], b = ac4[0];
          v[0]=a.x; v[1]=a.y; v[2]=a.z; v[3]=a.w; v[4]=b.x; v[5]=b.y; v[6]=b.z; v[7]=b.w;
        } else if (k0 < 80) {
          const float4 a = ac4[(k0 - 60) / 4], b = ac4[(k0 - 60) / 4 + 1];
          v[0]=a.x; v[1]=a.y; v[2]=a.z; v[3]=a.w; v[4]=b.x; v[5]=b.y; v[6]=b.z; v[7]=b.w;
        } else {
#pragma unroll
          for (int j = 0; j < 8; ++j) v[j] = 0.f;
        }
#pragma unroll
        for (int j = 0; j < 8; ++j) A1[kt][j] = (__bf16)v[j];
      }
    }

    // ---- Layer 1 (K 80: kt0/kt1 full + kt2 half-frag; A1[2] q>=2 is zero)
    f32x4 acc1[16];
#pragma unroll
    for (int nt = 0; nt < 16; ++nt) {
      f32x4 vv = {b1v[nt], b1v[nt], b1v[nt], b1v[nt]};
      acc1[nt] = vv;
    }
#pragma unroll
    for (int kt = 0; kt < 2; ++kt)
#pragma unroll
      for (int nt = 0; nt < 16; ++nt)
        acc1[nt] = __builtin_amdgcn_mfma_f32_16x16x32_bf16(
            A1[kt], *(const bf16x8*)(wl + (kt * 16 + nt) * 512 + lane * 8), acc1[nt], 0, 0, 0);
#pragma unroll
    for (int nt = 0; nt < 16; ++nt)
      acc1[nt] = __builtin_amdgcn_mfma_f32_16x16x32_bf16(
          A1[2], *(const bf16x8*)(wl + 16384 + nt * 256 + (lane & 31) * 8), acc1[nt], 0, 0, 0);

    // LN(256)+SiLU -> h1
    {
      float mu[4], rs[4];
#pragma unroll
      for (int r = 0; r < 4; ++r) {
        float s = 0.f, s2 = 0.f;
#pragma unroll
        for (int nt = 0; nt < 16; ++nt) { const float v = acc1[nt][r]; s += v; s2 += v * v; }
        s += __shfl_xor(s, 1); s2 += __shfl_xor(s2, 1);
        s += __shfl_xor(s, 2); s2 += __shfl_xor(s2, 2);
        s += __shfl_xor(s, 4); s2 += __shfl_xor(s2, 4);
        s += __shfl_xor(s, 8); s2 += __shfl_xor(s2, 8);
        const float m = s * (1.f / 256.f);
        mu[r] = m;
        rs[r] = rsqrtf(s2 * (1.f / 256.f) - m * m + 1e-5f);
      }
#pragma unroll
      for (int nt = 0; nt < 16; ++nt) {
        const int col = nt * 16 + c;
#pragma unroll
        for (int r = 0; r < 4; ++r) {
          float v = (acc1[nt][r] - mu[r]) * rs[r] * g1v[nt] + be1v[nt];
          v = v * __builtin_amdgcn_rcpf(1.f + __expf(-v));
          h1[(4 * q + r) * 264 + col] = (__bf16)v;
        }
      }
    }

    // ---- Layer 2 (K 256)
    f32x4 acc2[8];
#pragma unroll
    for (int nt = 0; nt < 8; ++nt) {
      f32x4 vv = {b2v[nt], b2v[nt], b2v[nt], b2v[nt]};
      acc2[nt] = vv;
    }
#pragma unroll
    for (int kt = 0; kt < 8; ++kt) {
      const bf16x8 A2 = *(const bf16x8*)(h1 + c * 264 + kt * 32 + q * 8);
#pragma unroll
      for (int nt = 0; nt < 8; ++nt)
        acc2[nt] = __builtin_amdgcn_mfma_f32_16x16x32_bf16(
            A2, *(const bf16x8*)(wl + 20480 + (kt * 8 + nt) * 512 + lane * 8), acc2[nt], 0, 0, 0);
    }
    // LN(128)+SiLU -> h2 (overlays h1 start; all h1 reads done)
    {
      float mu[4], rs[4];
#pragma unroll
      for (int r = 0; r < 4; ++r) {
        float s = 0.f, s2 = 0.f;
#pragma unroll
        for (int nt = 0; nt < 8; ++nt) { const float v = acc2[nt][r]; s += v; s2 += v * v; }
        s += __shfl_xor(s, 1); s2 += __shfl_xor(s2, 1);
        s += __shfl_xor(s, 2); s2 += __shfl_xor(s2, 2);
        s += __shfl_xor(s, 4); s2 += __shfl_xor(s2, 4);
        s += __shfl_xor(s, 8); s2 += __shfl_xor(s2, 8);
        const float m = s * (1.f / 128.f);
        mu[r] = m;
        rs[r] = rsqrtf(s2 * (1.f / 128.f) - m * m + 1e-5f);
      }
#pragma unroll
      for (int nt = 0; nt < 8; ++nt) {
        const int col = nt * 16 + c;
#pragma unroll
        for (int r = 0; r < 4; ++r) {
          float v = (acc2[nt][r] - mu[r]) * rs[r] * g2v[nt] + be2v[nt];
          v = v * __builtin_amdgcn_rcpf(1.f + __expf(-v));
          h2[(4 * q + r) * 136 + col] = (__bf16)v;
        }
      }
    }

    // ---- Layer 3 (K 128)
    f32x4 acc3[4];
#pragma unroll
    for (int nt = 0; nt < 4; ++nt) {
      f32x4 vv = {b3v[nt], b3v[nt], b3v[nt], b3v[nt]};
      acc3[nt] = vv;
    }
#pragma unroll
    for (int kt = 0; kt < 4; ++kt) {
      const bf16x8 A3 = *(const bf16x8*)(h2 + c * 136 + kt * 32 + q * 8);
#pragma unroll
      for (int nt = 0; nt < 4; ++nt)
        acc3[nt] = __builtin_amdgcn_mfma_f32_16x16x32_bf16(
            A3, *(const bf16x8*)(wl + 53248 + (kt * 4 + nt) * 512 + lane * 8), acc3[nt], 0, 0, 0);
    }
    // LN(64)+SiLU -> h3
    {
      float mu[4], rs[4];
#pragma unroll
      for (int r = 0; r < 4; ++r) {
        float s = 0.f, s2 = 0.f;
#pragma unroll
        for (int nt = 0; nt < 4; ++nt) { const float v = acc3[nt][r]; s += v; s2 += v * v; }
        s += __shfl_xor(s, 1); s2 += __shfl_xor(s2, 1);
        s += __shfl_xor(s, 2); s2 += __shfl_xor(s2, 2);
        s += __shfl_xor(s, 4); s2 += __shfl_xor(s2, 4);
        s += __shfl_xor(s, 8); s2 += __shfl_xor(s2, 8);
        const float m = s * (1.f / 64.f);
        mu[r] = m;
        rs[r] = rsqrtf(s2 * (1.f / 64.f) - m * m + 1e-5f);
      }
#pragma unroll
      for (int nt = 0; nt < 4; ++nt) {
        const int col = nt * 16 + c;
#pragma unroll
        for (int r = 0; r < 4; ++r) {
          float v = (acc3[nt][r] - mu[r]) * rs[r] * g3v[nt] + be3v[nt];
          v = v * __builtin_amdgcn_rcpf(1.f + __expf(-v));
          h3[(4 * q + r) * 72 + col] = (__bf16)v;
        }
      }
    }

    // ---- Layer 4 (register B-frags) + softmax + C51 projection
    f32x4 a4[7];
#pragma unroll
    for (int nt = 0; nt < 7; ++nt) {
      f32x4 vv = {b4v[nt], b4v[nt], b4v[nt], b4v[nt]};
      a4[nt] = vv;
    }
#pragma unroll
    for (int kt = 0; kt < 2; ++kt) {
      const bf16x8 A4 = *(const bf16x8*)(h3 + c * 72 + kt * 32 + q * 8);
#pragma unroll
      for (int nt = 0; nt < 7; ++nt)
        a4[nt] = __builtin_amdgcn_mfma_f32_16x16x32_bf16(A4, B4[kt][nt], a4[nt], 0, 0, 0);
    }

    {
      f32x4 z = {0.f, 0.f, 0.f, 0.f};
      f32x4* p4 = (f32x4*)proj;
      for (int i = lane; i < 404; i += 64) p4[i] = z;
    }
    float mx4[4] = {-3.4e38f, -3.4e38f, -3.4e38f, -3.4e38f};
#pragma unroll
    for (int nt = 0; nt < 7; ++nt) {
      const bool ok = (nt < 6) | (c < 5);
#pragma unroll
      for (int r = 0; r < 4; ++r)
        if (ok) mx4[r] = fmaxf(mx4[r], a4[nt][r]);
    }
#pragma unroll
    for (int r = 0; r < 4; ++r) {
      mx4[r] = fmaxf(mx4[r], __shfl_xor(mx4[r], 1));
      mx4[r] = fmaxf(mx4[r], __shfl_xor(mx4[r], 2));
      mx4[r] = fmaxf(mx4[r], __shfl_xor(mx4[r], 4));
      mx4[r] = fmaxf(mx4[r], __shfl_xor(mx4[r], 8));
    }
    float sm4[4] = {0.f, 0.f, 0.f, 0.f};
#pragma unroll
    for (int nt = 0; nt < 7; ++nt) {
      const bool ok = (nt < 6) | (c < 5);
#pragma unroll
      for (int r = 0; r < 4; ++r) {
        const float e = ok ? __expf(a4[nt][r] - mx4[r]) : 0.f;
        a4[nt][r] = e;
        sm4[r] += e;
      }
    }
    float inv4[4];
#pragma unroll
    for (int r = 0; r < 4; ++r) {
      float s = sm4[r];
      s += __shfl_xor(s, 1);
      s += __shfl_xor(s, 2);
      s += __shfl_xor(s, 4);
      s += __shfl_xor(s, 8);
      inv4[r] = __builtin_amdgcn_rcpf(s);
    }
    float rwv[4], bdv[4];
#pragma unroll
    for (int r = 0; r < 4; ++r) {
      const int gr = row0 + 4 * q + r;
      rwv[r] = rew[gr];
      bdv[r] = boot[gr] * disc[gr];
    }
#pragma unroll
    for (int nt = 0; nt < 7; ++nt) {
      if ((nt < 6) | (c < 5)) {
        const float qsvv = qsv[nt];
#pragma unroll
        for (int r = 0; r < 4; ++r) {
          const float p = a4[nt][r] * inv4[r];
          float tz = rwv[r] + bdv[r] * qsvv;
          tz = fminf(fmaxf(tz, -10.f), 10.f);
          const float b_ = (tz + 10.f) * 5.f;
          const float fl = floorf(b_), cl = ceilf(b_);
          int li = (int)fl, ui = (int)cl;
          if (ui == li) { if (li > 0) --li; else ++ui; }
          const int rb = (4 * q + r) * 101;
          atomicAdd(&proj[rb + li], p * ((float)ui - b_));
          atomicAdd(&proj[rb + ui], p * (b_ - (float)li));
        }
      }
    }

    // ---- coalesced writeout; proj reads precede next-iter h1 writes (in-order DS)
    {
      const f32x4* p4 = (const f32x4*)proj;
      f32x4* o4 = (f32x4*)(out + (size_t)row0 * 101);
      for (int i = lane; i < 404; i += 64) o4[i] = p4[i];
    }
  }
}

extern "C" void kernel_launch(void* const* d_in, const int* in_sizes, int n_in,
                              void* d_out, int out_size, void* d_ws, size_t ws_size,
                              hipStream_t stream)
{
  __bf16* ws = (__bf16*)d_ws;  // 137216 B used

  conv_weights<<<dim3(36), dim3(256), 0, stream>>>(
      (const float*)d_in[6], (const float*)d_in[10], (const float*)d_in[14],
      (const float*)d_in[18], ws);

  sacq_persist<<<dim3(256), dim3(256), 0, stream>>>(
      (const float*)d_in[0],  (const float*)d_in[1],  (const float*)d_in[2],
      (const float*)d_in[3],  (const float*)d_in[4],  (const float*)d_in[5],
      (const float*)d_in[7],  (const float*)d_in[8],  (const float*)d_in[9],
      (const float*)d_in[11], (const float*)d_in[12], (const float*)d_in[13],
      (const float*)d_in[15], (const float*)d_in[16], (const float*)d_in[17],
      (const float*)d_in[19], ws, (float*)d_out);
}